// Round 1
// baseline (244.051 us; speedup 1.0000x reference)
//
#include <hip/hip_runtime.h>

// HexagonalSensor photon binning: 16.7M photons -> 1801 hex pixels.
// Strategy: per-block LDS histogram (ds_add_f32 atomics) + LDS-staged lookup
// table; per-block partials in d_ws; second kernel reduces partials with only
// GROUPS global atomics per pixel. Memory-bound: ~201 MB streaming reads.

#define NPIX   1801      // 3*R*(R+1)+1 for R=24
#define LUTQ   49        // q dimension of lookup table
#define LUTR   49        // r dimension of lookup table
#define LUTN   (LUTQ * LUTR)
#define TPB    256
#define NBLK   1024      // histogram blocks (partial rows)
#define GROUPS 16        // reduction groups -> 16 atomics per pixel

__global__ __launch_bounds__(TPB) void hex_hist_kernel(
    const float* __restrict__ gx, const float* __restrict__ gy,
    const float* __restrict__ gv, const int* __restrict__ glut,
    const float* __restrict__ p_hs, const float* __restrict__ p_rot,
    const float* __restrict__ p_ox, const float* __restrict__ p_oy,
    const int* __restrict__ p_qmin, const int* __restrict__ p_rmin,
    const int* __restrict__ p_np,
    float* __restrict__ partials, float* __restrict__ out, int n)
{
    __shared__ float hist[NPIX];
    __shared__ int   lut[LUTN];

    const int tid = threadIdx.x;

    // zero LDS histogram + stage lookup table
    for (int i = tid; i < NPIX; i += TPB) hist[i] = 0.0f;
    for (int i = tid; i < LUTN; i += TPB) lut[i] = glut[i];
    // block 0 zeros the output (poisoned 0xAA before every timed launch);
    // safe because the reduce kernel runs strictly after us on the stream.
    if (blockIdx.x == 0) {
        const int np = p_np[0];
        for (int i = tid; i < np; i += TPB) out[i] = 0.0f;
    }
    __syncthreads();

    // wave-uniform scalars
    const float hs   = p_hs[0];
    const float rot  = p_rot[0];
    const float ox   = p_ox[0];
    const float oy   = p_oy[0];
    const int   qmin = p_qmin[0];
    const int   rmin = p_rmin[0];

    const float ca = cosf(-rot);
    const float sa = sinf(-rot);
    const float k1 = sqrtf(3.0f) / 3.0f;   // constant-folded in f32, matches XLA
    const float k2 = 2.0f / 3.0f;

    auto bin_one = [&](float px, float py, float pv) {
        const float xs = px - ox;
        const float ys = py - oy;
        const float xr = ca * xs - sa * ys;
        const float yr = sa * xs + ca * ys;
        // cartesian -> axial (pointy-top); true divisions to match reference
        const float q = (k1 * xr - yr / 3.0f) / hs;
        const float r = (k2 * yr) / hs;
        // axial round (round-half-even like jnp.round)
        const float s  = -q - r;
        float qr = rintf(q);
        float rr = rintf(r);
        const float sr = rintf(s);
        const float qd = fabsf(qr - q);
        const float rd = fabsf(rr - r);
        const float sd = fabsf(sr - s);
        if (qd > rd && qd > sd)      qr = -rr - sr;
        else if (rd > qd && rd > sd) rr = -qr - sr;  // mutually exclusive w/ above
        const int qi = (int)qr - qmin;
        const int ri = (int)rr - rmin;
        if (qi >= 0 && qi < LUTQ && ri >= 0 && ri < LUTR) {
            const int p = lut[qi * LUTR + ri];
            if (p >= 0) atomicAdd(&hist[p], pv);  // ds_add_f32, non-return
        }
        // invalid photons contribute exactly 0.0 in the reference -> skip
    };

    const int gthreads = gridDim.x * TPB;
    const int gtid     = blockIdx.x * TPB + tid;
    const int nvec     = n >> 2;

    const float4* x4 = (const float4*)gx;
    const float4* y4 = (const float4*)gy;
    const float4* v4 = (const float4*)gv;

    // software-pipelined grid-stride loop: next iteration's loads in flight
    // while the current 4 photons are binned.
    int i = gtid;
    if (i < nvec) {
        float4 a = x4[i], b = y4[i], v = v4[i];
        for (;;) {
            const int j = i + gthreads;
            const bool more = (j < nvec);
            float4 a2, b2, v2;
            if (more) { a2 = x4[j]; b2 = y4[j]; v2 = v4[j]; }
            bin_one(a.x, b.x, v.x);
            bin_one(a.y, b.y, v.y);
            bin_one(a.z, b.z, v.z);
            bin_one(a.w, b.w, v.w);
            if (!more) break;
            i = j; a = a2; b = b2; v = v2;
        }
    }
    // scalar tail (n not multiple of 4 — not expected here, but cheap)
    for (int t = (nvec << 2) + gtid; t < n; t += gthreads)
        bin_one(gx[t], gy[t], gv[t]);

    __syncthreads();

    // flush LDS histogram to this block's partial row (coalesced stores)
    float* prow = partials + (size_t)blockIdx.x * NPIX;
    for (int p = tid; p < NPIX; p += TPB) prow[p] = hist[p];
}

__global__ __launch_bounds__(TPB) void hex_reduce_kernel(
    const float* __restrict__ partials, float* __restrict__ out,
    const int* __restrict__ p_np, int rows_per_group)
{
    const int np = p_np[0];
    const int p  = blockIdx.x * TPB + threadIdx.x;
    if (p >= np || p >= NPIX) return;
    const int row0 = blockIdx.y * rows_per_group;
    float sum = 0.0f;
    #pragma unroll 8
    for (int b = 0; b < rows_per_group; ++b)
        sum += partials[(size_t)(row0 + b) * NPIX + p];
    atomicAdd(&out[p], sum);   // GROUPS atomics per pixel total
}

extern "C" void kernel_launch(void* const* d_in, const int* in_sizes, int n_in,
                              void* d_out, int out_size, void* d_ws, size_t ws_size,
                              hipStream_t stream) {
    const float* x      = (const float*)d_in[0];
    const float* y      = (const float*)d_in[1];
    const float* vals   = (const float*)d_in[2];
    const int*   lut    = (const int*)d_in[3];
    const float* hs     = (const float*)d_in[4];
    const float* rot    = (const float*)d_in[5];
    const float* offx   = (const float*)d_in[6];
    const float* offy   = (const float*)d_in[7];
    const int*   qmin   = (const int*)d_in[8];
    const int*   rmin   = (const int*)d_in[9];
    const int*   npix   = (const int*)d_in[10];
    float*       out    = (float*)d_out;
    float*       parts  = (float*)d_ws;
    const int    n      = in_sizes[0];

    // adapt partial-row count to workspace (normally 1024 rows = 7.4 MB)
    int nblk = NBLK;
    const size_t need = (size_t)NBLK * NPIX * sizeof(float);
    if (ws_size < need) {
        nblk = (int)(ws_size / (NPIX * sizeof(float)));
        nblk = (nblk / GROUPS) * GROUPS;
        if (nblk < GROUPS) nblk = GROUPS;
    }

    hipLaunchKernelGGL(hex_hist_kernel, dim3(nblk), dim3(TPB), 0, stream,
                       x, y, vals, lut, hs, rot, offx, offy, qmin, rmin, npix,
                       parts, out, n);

    const int rows_per_group = nblk / GROUPS;
    hipLaunchKernelGGL(hex_reduce_kernel,
                       dim3((NPIX + TPB - 1) / TPB, GROUPS), dim3(TPB), 0, stream,
                       parts, out, npix, rows_per_group);
}

// Round 3
// 243.948 us; speedup vs baseline: 1.0004x; 1.0004x over previous
//
#include <hip/hip_runtime.h>

// HexagonalSensor photon binning: 16.7M photons -> 1801 hex pixels.
// R2: latency/occupancy fixes. 2048 blocks (8/CU = 32 waves/CU, LDS-capped),
// divisions folded into a precomputed 2x2 linear transform, branchless
// axial rounding. Per-block LDS histogram (ds_add_f32) + LDS lookup table;
// partials in d_ws; second kernel reduces with GROUPS atomics/pixel.

#define NPIX   1801      // 3*R*(R+1)+1 for R=24
#define LUTQ   49
#define LUTR   49
#define LUTN   (LUTQ * LUTR)
#define TPB    256
#define NBLK   2048      // 8 blocks/CU * 256 CUs
#define GROUPS 32        // reduction groups -> 32 atomics per pixel

__global__ __launch_bounds__(TPB) void hex_hist_kernel(
    const float* __restrict__ gx, const float* __restrict__ gy,
    const float* __restrict__ gv, const int* __restrict__ glut,
    const float* __restrict__ p_hs, const float* __restrict__ p_rot,
    const float* __restrict__ p_ox, const float* __restrict__ p_oy,
    const int* __restrict__ p_qmin, const int* __restrict__ p_rmin,
    const int* __restrict__ p_np,
    float* __restrict__ partials, float* __restrict__ out, int n)
{
    __shared__ float hist[NPIX];
    __shared__ int   lut[LUTN];

    const int tid = threadIdx.x;

    for (int i = tid; i < NPIX; i += TPB) hist[i] = 0.0f;
    for (int i = tid; i < LUTN; i += TPB) lut[i] = glut[i];
    if (blockIdx.x == 0) {
        const int np = p_np[0];
        for (int i = tid; i < np; i += TPB) out[i] = 0.0f;
    }
    __syncthreads();

    // wave-uniform scalar setup: fold rotation + offset + axial transform
    // into q = Aq*x + Bq*y + Cq ; r = Ar*x + Br*y + Cr  (no divides in loop)
    const float hs   = p_hs[0];
    const float rot  = p_rot[0];
    const float ox   = p_ox[0];
    const float oy   = p_oy[0];
    const int   qmin = p_qmin[0];
    const int   rmin = p_rmin[0];

    const float ca = cosf(-rot);
    const float sa = sinf(-rot);
    const float k1 = sqrtf(3.0f) / 3.0f;
    const float inv_hs = 1.0f / hs;
    // q = (k1*xr - yr/3)/hs, r = (2/3)*yr/hs with
    // xr = ca*xs - sa*ys, yr = sa*xs + ca*ys, xs = x-ox, ys = y-oy
    const float Aq = (k1 * ca - sa * (1.0f / 3.0f)) * inv_hs;
    const float Bq = (-k1 * sa - ca * (1.0f / 3.0f)) * inv_hs;
    const float Ar = ((2.0f / 3.0f) * sa) * inv_hs;
    const float Br = ((2.0f / 3.0f) * ca) * inv_hs;
    const float Cq = -(Aq * ox + Bq * oy);
    const float Cr = -(Ar * ox + Br * oy);

    auto bin_one = [&](float px, float py, float pv) {
        const float q = fmaf(Aq, px, fmaf(Bq, py, Cq));
        const float r = fmaf(Ar, px, fmaf(Br, py, Cr));
        const float s = -q - r;
        const float qr0 = rintf(q);   // v_rndne: round-half-even like jnp.round
        const float rr0 = rintf(r);
        const float sr0 = rintf(s);
        const float qd = fabsf(qr0 - q);
        const float rd = fabsf(rr0 - r);
        const float sd = fabsf(sr0 - s);
        // conditions are mutually exclusive -> branchless cndmask
        const bool c1 = (qd > rd) && (qd > sd);
        const bool c2 = (rd > qd) && (rd > sd);
        const float qf = c1 ? (-rr0 - sr0) : qr0;
        const float rf = c2 ? (-qr0 - sr0) : rr0;
        const int qi = (int)qf - qmin;
        const int ri = (int)rf - rmin;
        if ((unsigned)qi < LUTQ && (unsigned)ri < LUTR) {
            const int p = lut[qi * LUTR + ri];
            if (p >= 0) atomicAdd(&hist[p], pv);   // ds_add_f32 non-return
        }
    };

    const int gthreads = gridDim.x * TPB;
    const int gtid     = blockIdx.x * TPB + tid;
    const int nvec     = n >> 2;

    const float4* x4 = (const float4*)gx;
    const float4* y4 = (const float4*)gy;
    const float4* v4 = (const float4*)gv;

    // 1-deep software pipeline: next 3 float4 loads in flight during binning
    int i = gtid;
    if (i < nvec) {
        float4 a = x4[i], b = y4[i], v = v4[i];
        for (;;) {
            const int j = i + gthreads;
            const bool more = (j < nvec);
            float4 a2, b2, v2;
            if (more) { a2 = x4[j]; b2 = y4[j]; v2 = v4[j]; }
            bin_one(a.x, b.x, v.x);
            bin_one(a.y, b.y, v.y);
            bin_one(a.z, b.z, v.z);
            bin_one(a.w, b.w, v.w);
            if (!more) break;
            i = j; a = a2; b = b2; v = v2;
        }
    }
    for (int t = (nvec << 2) + gtid; t < n; t += gthreads)
        bin_one(gx[t], gy[t], gv[t]);

    __syncthreads();

    float* prow = partials + (size_t)blockIdx.x * NPIX;
    for (int p = tid; p < NPIX; p += TPB) prow[p] = hist[p];
}

__global__ __launch_bounds__(TPB) void hex_reduce_kernel(
    const float* __restrict__ partials, float* __restrict__ out,
    const int* __restrict__ p_np, int rows_per_group)
{
    const int np = p_np[0];
    const int p  = blockIdx.x * TPB + threadIdx.x;
    if (p >= np || p >= NPIX) return;
    const int row0 = blockIdx.y * rows_per_group;
    float sum = 0.0f;
    #pragma unroll 8
    for (int b = 0; b < rows_per_group; ++b)
        sum += partials[(size_t)(row0 + b) * NPIX + p];
    atomicAdd(&out[p], sum);
}

extern "C" void kernel_launch(void* const* d_in, const int* in_sizes, int n_in,
                              void* d_out, int out_size, void* d_ws, size_t ws_size,
                              hipStream_t stream) {
    const float* x      = (const float*)d_in[0];
    const float* y      = (const float*)d_in[1];
    const float* vals   = (const float*)d_in[2];
    const int*   lut    = (const int*)d_in[3];
    const float* hs     = (const float*)d_in[4];
    const float* rot    = (const float*)d_in[5];
    const float* offx   = (const float*)d_in[6];
    const float* offy   = (const float*)d_in[7];
    const int*   qmin   = (const int*)d_in[8];
    const int*   rmin   = (const int*)d_in[9];
    const int*   npix   = (const int*)d_in[10];
    float*       out    = (float*)d_out;
    float*       parts  = (float*)d_ws;
    const int    n      = in_sizes[0];

    // adapt partial-row count to workspace (target 2048 rows = 14.8 MB)
    int nblk = NBLK;
    const size_t row_bytes = (size_t)NPIX * sizeof(float);
    if (ws_size < (size_t)NBLK * row_bytes) {
        nblk = (int)(ws_size / row_bytes);
        nblk = (nblk / GROUPS) * GROUPS;
        if (nblk < GROUPS) nblk = GROUPS;
    }

    hipLaunchKernelGGL(hex_hist_kernel, dim3(nblk), dim3(TPB), 0, stream,
                       x, y, vals, lut, hs, rot, offx, offy, qmin, rmin, npix,
                       parts, out, n);

    const int rows_per_group = nblk / GROUPS;
    hipLaunchKernelGGL(hex_reduce_kernel,
                       dim3((NPIX + TPB - 1) / TPB, GROUPS), dim3(TPB), 0, stream,
                       parts, out, npix, rows_per_group);
}